// Round 4
// baseline (195.681 us; speedup 1.0000x reference)
//
#include <hip/hip_runtime.h>

// CPRPackedLinear: out(64x11008) = xperm[:, :1024] @ deq6(W_high) + xperm[:, 1024:] @ deq5(W_low) + bias
// R4: LDS-free design. M=64 lives in ONE wave as 4 m-tiles, so each lane
// dequantizes exactly the B-fragment it consumes (no sharing -> no LDS, no
// barriers, no block-wide drains). 2-deep register pipeline per wave; one
// merged gemm launch (grid 172x8); 4 adjacent n-tiles per block so the
// 64B-per-quad weight reads pair up in L1. Harness overhead (~120us of ws
// poison + input restore) is outside our control; we minimize kernel sum.

#define NFEAT 11008
#define KTOT  4096

typedef _Float16 half8 __attribute__((ext_vector_type(8)));
typedef _Float16 half2 __attribute__((ext_vector_type(2)));
typedef float    f32x4 __attribute__((ext_vector_type(4)));

union H8 { half8 v; half2 h[4]; _Float16 e[8]; };

// (1024+a, 1024+b) as packed fp16 (exact for 0..255), then (h-off)*s pk-f16.
__device__ __forceinline__ half2 dq2(int a, int b, half2 off, half2 s) {
    unsigned u = 0x64006400u | (unsigned)a | ((unsigned)b << 16);
    half2 h = __builtin_bit_cast(half2, u);
    return (h - off) * s;
}

// ---------------- prep: x_perm -> fp16 in MFMA A-fragment layout ----------------
// xfrag chunk u = (sg*4 + mt)*64 + lane holds 8 halves:
//   x[m = mt*16 + (lane&15)][ col[k = sg*32 + (lane>>4)*8 + j] ], j=0..7
__global__ __launch_bounds__(256) void prep_xfrag(const float* __restrict__ x,
                                                  const int* __restrict__ col,
                                                  _Float16* __restrict__ xfrag) {
    int u  = blockIdx.x * 256 + threadIdx.x;   // 0..32767
    int l  = u & 63;
    int mt = (u >> 6) & 3;
    int s  = u >> 8;
    int m  = mt * 16 + (l & 15);
    int kb = s * 32 + ((l >> 4) << 3);
    H8 w;
#pragma unroll
    for (int j = 0; j < 8; ++j)
        w.e[j] = (_Float16)x[m * KTOT + col[kb + j]];
    *(half8*)(xfrag + (size_t)u * 8) = w.v;
}

// ---------------- per-wave 512-k chunk, register-direct B ----------------
// kloc: region-local k of chunk start; sgbase: global k>>5 of chunk start.
// n: this lane's output column; quad = lane>>4.
template <bool HIGH>
__device__ __forceinline__ void run_chunk(const int* __restrict__ W,
                                          const float* __restrict__ S,
                                          const _Float16* __restrict__ xfrag,
                                          int kloc, int sgbase,
                                          int n, int quad, int lane,
                                          f32x4 acc[4]) {
    constexpr int NR = HIGH ? 6 : 5;
    int   raw[2][6];
    float sc[2];
    half8 a[2][4];

    auto issue = [&](int t, int st) {
        const int k0  = kloc + t * 32 + quad * 8;
        const int row = HIGH ? 3 * (k0 >> 2) : 5 * (k0 >> 3);
        const int* p  = W + (size_t)row * NFEAT + n;
#pragma unroll
        for (int r = 0; r < NR; ++r) raw[st][r] = p[(size_t)r * NFEAT];
        sc[st] = S[(size_t)((kloc + t * 32) >> 7) * NFEAT + n];
        const int sg = sgbase + t;
#pragma unroll
        for (int mt = 0; mt < 4; ++mt)
            a[st][mt] = *(const half8*)(xfrag + (size_t)((sg * 4 + mt) * 64 + lane) * 8);
    };

    auto consume = [&](int st) {
        int v0, v1, v2, v3, v4, v5, v6, v7;
        if constexpr (HIGH) {
            int b0 = raw[st][0], b1 = raw[st][1], b2 = raw[st][2],
                b3 = raw[st][3], b4 = raw[st][4], b5 = raw[st][5];
            v0 = b0 & 63;
            v1 = ((b0 >> 6) & 3) | ((b1 & 15) << 2);
            v2 = ((b1 >> 4) & 15) | ((b2 & 3) << 4);
            v3 = (b2 >> 2) & 63;
            v4 = b3 & 63;
            v5 = ((b3 >> 6) & 3) | ((b4 & 15) << 2);
            v6 = ((b4 >> 4) & 15) | ((b5 & 3) << 4);
            v7 = (b5 >> 2) & 63;
        } else {
            int b0 = raw[st][0], b1 = raw[st][1], b2 = raw[st][2],
                b3 = raw[st][3], b4 = raw[st][4];
            v0 = b0 & 31;
            v1 = ((b0 >> 5) & 7) | ((b1 & 3) << 3);
            v2 = (b1 >> 2) & 31;
            v3 = ((b1 >> 7) & 1) | ((b2 & 15) << 1);
            v4 = ((b2 >> 4) & 15) | ((b3 & 1) << 4);
            v5 = (b3 >> 1) & 31;
            v6 = ((b3 >> 6) & 3) | ((b4 & 7) << 2);
            v7 = (b4 >> 3) & 31;
        }
        const _Float16 ofv = HIGH ? (_Float16)1055.0f : (_Float16)1039.0f;
        const half2 off = {ofv, ofv};
        _Float16 s1 = (_Float16)sc[st];
        half2 s2 = {s1, s1};
        H8 w;
        w.h[0] = dq2(v0, v1, off, s2);
        w.h[1] = dq2(v2, v3, off, s2);
        w.h[2] = dq2(v4, v5, off, s2);
        w.h[3] = dq2(v6, v7, off, s2);
#pragma unroll
        for (int mt = 0; mt < 4; ++mt)
            acc[mt] = __builtin_amdgcn_mfma_f32_16x16x32_f16(a[st][mt], w.v, acc[mt], 0, 0, 0);
    };

    issue(0, 0);
#pragma unroll
    for (int t = 0; t < 16; ++t) {
        if (t + 1 < 16) issue(t + 1, (t + 1) & 1);   // in flight during consume(t)
        consume(t & 1);
    }
}

// ---------------- main GEMM: one launch, grid (172, 8/nsub) ----------------
// Each wave: n-tile of 16 cols (block covers 64), nsub*512 k rows.
__global__ __launch_bounds__(256, 4) void gemm_kernel(const int* __restrict__ Wh,
                                                      const int* __restrict__ Wl,
                                                      const float* __restrict__ sh,
                                                      const float* __restrict__ sl,
                                                      const _Float16* __restrict__ xfrag,
                                                      float* __restrict__ dst,
                                                      int nsub, int atomic_mode) {
    const int lane = threadIdx.x & 63;
    const int wave = threadIdx.x >> 6;
    const int quad = lane >> 4;
    const int n    = blockIdx.x * 64 + wave * 16 + (lane & 15);

    f32x4 acc[4];
#pragma unroll
    for (int i = 0; i < 4; ++i) acc[i] = (f32x4){0.f, 0.f, 0.f, 0.f};

    for (int s = 0; s < nsub; ++s) {
        const int kglob  = (blockIdx.y * nsub + s) * 512;
        const int sgbase = kglob >> 5;
        if (kglob < 1024)
            run_chunk<true >(Wh, sh, xfrag, kglob,        sgbase, n, quad, lane, acc);
        else
            run_chunk<false>(Wl, sl, xfrag, kglob - 1024, sgbase, n, quad, lane, acc);
    }

    // epilogue: D row = mt*16 + quad*4 + r, col = n
    const int rb = quad << 2;
    if (atomic_mode) {
#pragma unroll
        for (int mt = 0; mt < 4; ++mt)
#pragma unroll
            for (int r = 0; r < 4; ++r)
                atomicAdd(&dst[(size_t)(mt * 16 + rb + r) * NFEAT + n], acc[mt][r]);
    } else {
        float* o = dst + (size_t)blockIdx.y * 64 * NFEAT;
#pragma unroll
        for (int mt = 0; mt < 4; ++mt)
#pragma unroll
            for (int r = 0; r < 4; ++r)
                o[(size_t)(mt * 16 + rb + r) * NFEAT + n] = acc[mt][r];
    }
}

// ---------------- reduce: out = bias + sum_p partial[p] ----------------
__global__ __launch_bounds__(256) void reduce_out(const float* __restrict__ part,
                                                  const float* __restrict__ bias,
                                                  float* __restrict__ out, int P) {
    const int idx = blockIdx.x * 256 + threadIdx.x;   // 0..176127 (f32x4 units)
    const int f   = idx * 4;
    const int nn  = f % NFEAT;                        // NFEAT%4==0 -> same row
    f32x4 s = *(const f32x4*)(bias + nn);
    for (int p = 0; p < P; ++p)
        s += *(const f32x4*)(part + (size_t)p * 704512 + f);
    *(f32x4*)(out + f) = s;
}

__global__ __launch_bounds__(256) void init_bias(const float* __restrict__ bias,
                                                 float* __restrict__ out) {
    const int idx = blockIdx.x * 256 + threadIdx.x;   // 0..704511
    out[idx] = bias[idx % NFEAT];
}

extern "C" void kernel_launch(void* const* d_in, const int* in_sizes, int n_in,
                              void* d_out, int out_size, void* d_ws, size_t ws_size,
                              hipStream_t stream) {
    const float* x    = (const float*)d_in[0];
    const int*   Wh   = (const int*)d_in[1];
    const int*   Wl   = (const int*)d_in[2];
    const float* sh   = (const float*)d_in[3];
    const float* sl   = (const float*)d_in[4];
    const int*   col  = (const int*)d_in[5];
    const float* bias = (const float*)d_in[6];
    float* out = (float*)d_out;

    _Float16* xfrag = (_Float16*)d_ws;                         // 512 KB
    const size_t xb      = (size_t)64 * KTOT * sizeof(_Float16);
    const size_t pstride = (size_t)64 * NFEAT;                 // floats per partial

    prep_xfrag<<<128, 256, 0, stream>>>(x, col, xfrag);

    if (ws_size >= xb + 8 * pstride * sizeof(float)) {
        float* part = (float*)((char*)d_ws + xb);
        gemm_kernel<<<dim3(172, 8), 256, 0, stream>>>(Wh, Wl, sh, sl, xfrag, part, 1, 0);
        reduce_out<<<688, 256, 0, stream>>>(part, bias, out, 8);
    } else if (ws_size >= xb + 4 * pstride * sizeof(float)) {
        float* part = (float*)((char*)d_ws + xb);
        gemm_kernel<<<dim3(172, 4), 256, 0, stream>>>(Wh, Wl, sh, sl, xfrag, part, 2, 0);
        reduce_out<<<688, 256, 0, stream>>>(part, bias, out, 4);
    } else {
        init_bias<<<2752, 256, 0, stream>>>(bias, out);
        gemm_kernel<<<dim3(172, 8), 256, 0, stream>>>(Wh, Wl, sh, sl, xfrag, out, 1, 1);
    }
}

// Round 5
// 191.389 us; speedup vs baseline: 1.0224x; 1.0224x over previous
//
#include <hip/hip_runtime.h>

// CPRPackedLinear: out(64x11008) = xperm[:, :1024] @ deq6(W_high) + xperm[:, 1024:] @ deq5(W_low) + bias
// R5: R4's failure = compiler collapsed the software pipeline (VGPR=56 proves
// no prefetch state was live -> full HBM latency exposed per k-step). Fix:
// explicit double-buffered stage structs consumed across a #pragma unroll 1
// back-edge -> compiler is FORCED to keep ~25 loads (12KB) in flight per wave.
// Still LDS-free / barrier-free: one wave owns all of M=64 (4 m-tiles), each
// lane dequantizes exactly the B-fragment it feeds to MFMA.

#define NFEAT 11008
#define KTOT  4096

typedef _Float16 half8 __attribute__((ext_vector_type(8)));
typedef _Float16 half2 __attribute__((ext_vector_type(2)));
typedef float    f32x4 __attribute__((ext_vector_type(4)));

union H8 { half8 v; half2 h[4]; _Float16 e[8]; };

// (1024+a, 1024+b) as packed fp16 (exact for 0..255), then (h-off)*s pk-f16.
__device__ __forceinline__ half2 dq2(int a, int b, half2 off, half2 s) {
    unsigned u = 0x64006400u | (unsigned)a | ((unsigned)b << 16);
    half2 h = __builtin_bit_cast(half2, u);
    return (h - off) * s;
}

// ---------------- prep: x_perm -> fp16 in MFMA A-fragment layout ----------------
// xfrag chunk u = (sg*4 + mt)*64 + lane holds 8 halves:
//   x[m = mt*16 + (lane&15)][ col[k = sg*32 + (lane>>4)*8 + j] ], j=0..7
__global__ __launch_bounds__(256) void prep_xfrag(const float* __restrict__ x,
                                                  const int* __restrict__ col,
                                                  _Float16* __restrict__ xfrag) {
    int u  = blockIdx.x * 256 + threadIdx.x;   // 0..32767
    int l  = u & 63;
    int mt = (u >> 6) & 3;
    int s  = u >> 8;
    int m  = mt * 16 + (l & 15);
    int kb = s * 32 + ((l >> 4) << 3);
    H8 w;
#pragma unroll
    for (int j = 0; j < 8; ++j)
        w.e[j] = (_Float16)x[m * KTOT + col[kb + j]];
    *(half8*)(xfrag + (size_t)u * 8) = w.v;
}

// ---------------- pipelined 512-k chunk, register-direct B ----------------
// Stage = one 64-k batch (2 MFMA k-steps): 12(10) raw ints + 8 A-frags + scale.
template <bool HIGH>
struct Stage {
    int   raw[HIGH ? 12 : 10];
    half8 a[8];
    float sc;
};

template <bool HIGH>
__device__ __forceinline__ void issue_batch(const int* __restrict__ Wlane,
                                            const float* __restrict__ Slane,
                                            const _Float16* __restrict__ Abase,
                                            int b, Stage<HIGH>& S) {
    constexpr int NR   = HIGH ? 6 : 5;
    constexpr int RPSG = HIGH ? 24 : 20;      // packed int-rows per 32 k
#pragma unroll
    for (int s = 0; s < 2; ++s) {
        const int* p = Wlane + (size_t)(b * 2 * RPSG + s * RPSG) * NFEAT;
#pragma unroll
        for (int r = 0; r < NR; ++r)
            S.raw[s * NR + r] = p[(size_t)r * NFEAT];
    }
    S.sc = Slane[(size_t)(b >> 1) * NFEAT];   // GROUP=128k, batch=64k aligned
#pragma unroll
    for (int s = 0; s < 2; ++s)
#pragma unroll
        for (int mt = 0; mt < 4; ++mt)
            S.a[s * 4 + mt] = *(const half8*)(Abase + ((size_t)(b * 2 + s) * 4 + mt) * 512);
}

template <bool HIGH>
__device__ __forceinline__ void consume_batch(const Stage<HIGH>& S, f32x4 acc[4]) {
    constexpr int NR = HIGH ? 6 : 5;
    const _Float16 ofv = HIGH ? (_Float16)1055.0f : (_Float16)1039.0f;
    const half2 off = {ofv, ofv};
    const _Float16 s1 = (_Float16)S.sc;
    const half2 s2 = {s1, s1};
#pragma unroll
    for (int s = 0; s < 2; ++s) {
        int v0, v1, v2, v3, v4, v5, v6, v7;
        if constexpr (HIGH) {
            int b0 = S.raw[s * 6 + 0], b1 = S.raw[s * 6 + 1], b2 = S.raw[s * 6 + 2],
                b3 = S.raw[s * 6 + 3], b4 = S.raw[s * 6 + 4], b5 = S.raw[s * 6 + 5];
            v0 = b0 & 63;
            v1 = ((b0 >> 6) & 3) | ((b1 & 15) << 2);
            v2 = ((b1 >> 4) & 15) | ((b2 & 3) << 4);
            v3 = (b2 >> 2) & 63;
            v4 = b3 & 63;
            v5 = ((b3 >> 6) & 3) | ((b4 & 15) << 2);
            v6 = ((b4 >> 4) & 15) | ((b5 & 3) << 4);
            v7 = (b5 >> 2) & 63;
        } else {
            int b0 = S.raw[s * 5 + 0], b1 = S.raw[s * 5 + 1], b2 = S.raw[s * 5 + 2],
                b3 = S.raw[s * 5 + 3], b4 = S.raw[s * 5 + 4];
            v0 = b0 & 31;
            v1 = ((b0 >> 5) & 7) | ((b1 & 3) << 3);
            v2 = (b1 >> 2) & 31;
            v3 = ((b1 >> 7) & 1) | ((b2 & 15) << 1);
            v4 = ((b2 >> 4) & 15) | ((b3 & 1) << 4);
            v5 = (b3 >> 1) & 31;
            v6 = ((b3 >> 6) & 3) | ((b4 & 7) << 2);
            v7 = (b4 >> 3) & 31;
        }
        H8 w;
        w.h[0] = dq2(v0, v1, off, s2);
        w.h[1] = dq2(v2, v3, off, s2);
        w.h[2] = dq2(v4, v5, off, s2);
        w.h[3] = dq2(v6, v7, off, s2);
#pragma unroll
        for (int mt = 0; mt < 4; ++mt)
            acc[mt] = __builtin_amdgcn_mfma_f32_16x16x32_f16(S.a[s * 4 + mt], w.v, acc[mt], 0, 0, 0);
    }
}

template <bool HIGH>
__device__ __forceinline__ void run_chunk(const int* __restrict__ W,
                                          const float* __restrict__ Sg,
                                          const _Float16* __restrict__ xfrag,
                                          int kloc, int sgbase,
                                          int n, int quad, int lane,
                                          f32x4 acc[4]) {
    const int row0 = HIGH ? (3 * (kloc >> 2) + 6 * quad) : (5 * (kloc >> 3) + 5 * quad);
    const int* Wlane       = W + (size_t)row0 * NFEAT + n;
    const float* Slane     = Sg + (size_t)(kloc >> 7) * NFEAT + n;
    const _Float16* Abase  = xfrag + (size_t)sgbase * 4 * 512 + lane * 8;

    Stage<HIGH> S0, S1;
    issue_batch<HIGH>(Wlane, Slane, Abase, 0, S0);
    issue_batch<HIGH>(Wlane, Slane, Abase, 1, S1);
    // S0/S1 written one iteration, consumed the next -> forced 2-deep pipeline.
#pragma unroll 1
    for (int b = 0; b < 6; b += 2) {
        consume_batch<HIGH>(S0, acc);
        issue_batch<HIGH>(Wlane, Slane, Abase, b + 2, S0);
        consume_batch<HIGH>(S1, acc);
        issue_batch<HIGH>(Wlane, Slane, Abase, b + 3, S1);
    }
    consume_batch<HIGH>(S0, acc);
    consume_batch<HIGH>(S1, acc);
}

// ---------------- main GEMM: one launch, grid (172, 8/nsub) ----------------
// Each wave: 16 cols (block covers 64), nsub*512 k rows, all 4 m-tiles.
__global__ __launch_bounds__(256, 3) void gemm_kernel(const int* __restrict__ Wh,
                                                      const int* __restrict__ Wl,
                                                      const float* __restrict__ sh,
                                                      const float* __restrict__ sl,
                                                      const _Float16* __restrict__ xfrag,
                                                      float* __restrict__ dst,
                                                      int nsub, int atomic_mode) {
    const int lane = threadIdx.x & 63;
    const int wave = threadIdx.x >> 6;
    const int quad = lane >> 4;
    const int n    = blockIdx.x * 64 + wave * 16 + (lane & 15);

    f32x4 acc[4];
#pragma unroll
    for (int i = 0; i < 4; ++i) acc[i] = (f32x4){0.f, 0.f, 0.f, 0.f};

    for (int s = 0; s < nsub; ++s) {
        const int kglob  = (blockIdx.y * nsub + s) * 512;
        const int sgbase = kglob >> 5;
        if (kglob < 1024)
            run_chunk<true >(Wh, sh, xfrag, kglob,        sgbase, n, quad, lane, acc);
        else
            run_chunk<false>(Wl, sl, xfrag, kglob - 1024, sgbase, n, quad, lane, acc);
    }

    // epilogue: D row = mt*16 + quad*4 + r, col = n
    const int rb = quad << 2;
    if (atomic_mode) {
#pragma unroll
        for (int mt = 0; mt < 4; ++mt)
#pragma unroll
            for (int r = 0; r < 4; ++r)
                atomicAdd(&dst[(size_t)(mt * 16 + rb + r) * NFEAT + n], acc[mt][r]);
    } else {
        float* o = dst + (size_t)blockIdx.y * 64 * NFEAT;
#pragma unroll
        for (int mt = 0; mt < 4; ++mt)
#pragma unroll
            for (int r = 0; r < 4; ++r)
                o[(size_t)(mt * 16 + rb + r) * NFEAT + n] = acc[mt][r];
    }
}

// ---------------- reduce: out = bias + sum_p partial[p] ----------------
__global__ __launch_bounds__(256) void reduce_out(const float* __restrict__ part,
                                                  const float* __restrict__ bias,
                                                  float* __restrict__ out, int P) {
    const int idx = blockIdx.x * 256 + threadIdx.x;   // 0..176127 (f32x4 units)
    const int f   = idx * 4;
    const int nn  = f % NFEAT;                        // NFEAT%4==0 -> same row
    f32x4 s = *(const f32x4*)(bias + nn);
    for (int p = 0; p < P; ++p)
        s += *(const f32x4*)(part + (size_t)p * 704512 + f);
    *(f32x4*)(out + f) = s;
}

__global__ __launch_bounds__(256) void init_bias(const float* __restrict__ bias,
                                                 float* __restrict__ out) {
    const int idx = blockIdx.x * 256 + threadIdx.x;   // 0..704511
    out[idx] = bias[idx % NFEAT];
}

extern "C" void kernel_launch(void* const* d_in, const int* in_sizes, int n_in,
                              void* d_out, int out_size, void* d_ws, size_t ws_size,
                              hipStream_t stream) {
    const float* x    = (const float*)d_in[0];
    const int*   Wh   = (const int*)d_in[1];
    const int*   Wl   = (const int*)d_in[2];
    const float* sh   = (const float*)d_in[3];
    const float* sl   = (const float*)d_in[4];
    const int*   col  = (const int*)d_in[5];
    const float* bias = (const float*)d_in[6];
    float* out = (float*)d_out;

    _Float16* xfrag = (_Float16*)d_ws;                         // 512 KB
    const size_t xb      = (size_t)64 * KTOT * sizeof(_Float16);
    const size_t pstride = (size_t)64 * NFEAT;                 // floats per partial

    prep_xfrag<<<128, 256, 0, stream>>>(x, col, xfrag);

    if (ws_size >= xb + 8 * pstride * sizeof(float)) {
        float* part = (float*)((char*)d_ws + xb);
        gemm_kernel<<<dim3(172, 8), 256, 0, stream>>>(Wh, Wl, sh, sl, xfrag, part, 1, 0);
        reduce_out<<<688, 256, 0, stream>>>(part, bias, out, 8);
    } else if (ws_size >= xb + 4 * pstride * sizeof(float)) {
        float* part = (float*)((char*)d_ws + xb);
        gemm_kernel<<<dim3(172, 4), 256, 0, stream>>>(Wh, Wl, sh, sl, xfrag, part, 2, 0);
        reduce_out<<<688, 256, 0, stream>>>(part, bias, out, 4);
    } else {
        init_bias<<<2752, 256, 0, stream>>>(bias, out);
        gemm_kernel<<<dim3(172, 8), 256, 0, stream>>>(Wh, Wl, sh, sl, xfrag, out, 1, 1);
    }
}

// Round 6
// 184.668 us; speedup vs baseline: 1.0596x; 1.0364x over previous
//
#include <hip/hip_runtime.h>

// CPRPackedLinear: out(64x11008) = xperm[:, :1024] @ deq6(W_high) + xperm[:, 1024:] @ deq5(W_low) + bias
// R6: three rounds prove source-level register pipelining is collapsed by the
// compiler (R5: VGPR=84 -> one live stage) and all register-direct variants
// plateau at ~1.3 TB/s (in-flight ~2KB/CU vs 9KB BDP). Switch to the proven
// m97 structure: global_load_lds stages packed W into LDS (in-flight bytes
// cost zero VGPRs -> compiler can't collapse), barrier-drained 64-k tiles,
// latency hidden by 4-5 resident blocks/CU (m114 implicit overlap).
// Row-rotated LDS layout gives conflict-free ds_reads without padding
// (global_load_lds forces lane-linear dest). Waves split n (no dequant
// redundancy); each lane dequants exactly the B-fragment it feeds to MFMA.

#define NFEAT 11008
#define KTOT  4096

typedef _Float16 half8 __attribute__((ext_vector_type(8)));
typedef _Float16 half2 __attribute__((ext_vector_type(2)));
typedef float    f32x4 __attribute__((ext_vector_type(4)));

union H8 { half8 v; half2 h[4]; _Float16 e[8]; };

// (1024+a, 1024+b) as packed fp16 (exact for 0..255), then (h-off)*s pk-f16.
__device__ __forceinline__ half2 dq2(int a, int b, half2 off, half2 s) {
    unsigned u = 0x64006400u | (unsigned)a | ((unsigned)b << 16);
    half2 h = __builtin_bit_cast(half2, u);
    return (h - off) * s;
}

// async 16B-per-lane global->LDS (dest = uniform base + lane*16)
#define GLOAD_LDS16(gp, lp)                                             \
    __builtin_amdgcn_global_load_lds(                                   \
        (const __attribute__((address_space(1))) void*)(gp),            \
        (__attribute__((address_space(3))) void*)(lp), 16, 0, 0)

// ---------------- prep: x_perm -> fp16 in MFMA A-fragment layout ----------------
// xfrag chunk u = (sg*4 + mt)*64 + lane holds 8 halves:
//   x[m = mt*16 + (lane&15)][ col[k = sg*32 + (lane>>4)*8 + j] ], j=0..7
__global__ __launch_bounds__(256) void prep_xfrag(const float* __restrict__ x,
                                                  const int* __restrict__ col,
                                                  _Float16* __restrict__ xfrag) {
    int u  = blockIdx.x * 256 + threadIdx.x;   // 0..32767
    int l  = u & 63;
    int mt = (u >> 6) & 3;
    int s  = u >> 8;
    int m  = mt * 16 + (l & 15);
    int kb = s * 32 + ((l >> 4) << 3);
    H8 w;
#pragma unroll
    for (int j = 0; j < 8; ++j)
        w.e[j] = (_Float16)x[m * KTOT + col[kb + j]];
    *(half8*)(xfrag + (size_t)u * 8) = w.v;
}

// ---------------- main GEMM: grid (172, 8), block 256 ----------------
// Block: n-tile 64 cols (wave w owns cols n0+16w..+15), k-chunk 512
// (ky<2: 6-bit high region, else 5-bit low). Per 64-k tile: stage packed
// rows into LDS (row r at lds[r*64 ints], col-groups rotated by r mod 16),
// then dequant+MFMA. Two barriers/tile, single LDS buffer (m97 pattern).
__global__ __launch_bounds__(256, 4) void gemm_kernel(const int* __restrict__ Wh,
                                                      const int* __restrict__ Wl,
                                                      const float* __restrict__ sh,
                                                      const float* __restrict__ sl,
                                                      const _Float16* __restrict__ xfrag,
                                                      float* __restrict__ dst,
                                                      int atomic_mode) {
    const int n0   = blockIdx.x * 64;
    const int ky   = blockIdx.y;
    const int lane = threadIdx.x & 63;
    const int wave = threadIdx.x >> 6;
    const int quad = lane >> 4;
    const int nl   = lane & 15;
    const int n    = n0 + wave * 16 + nl;

    const bool high  = (ky < 2);
    const int  kloc0 = high ? ky * 512 : (ky * 512 - 1024);  // region-local chunk start

    const int*   Wb = high ? Wh : Wl;
    const float* Sb = high ? sh : sl;
    const int NI  = high ? 12 : 10;                  // stage instrs per tile (4 rows each)
    const int RPT = high ? 48 : 40;                  // packed rows per 64-k tile
    const int R00 = high ? 3 * (kloc0 >> 2) : 5 * (kloc0 >> 3);

    __shared__ int lds[48 * 64];                     // 12 KB

    f32x4 acc[4];
#pragma unroll
    for (int i = 0; i < 4; ++i) acc[i] = (f32x4){0.f, 0.f, 0.f, 0.f};

    const int srow = lane >> 4;                      // staging: row-within-instr
    const int spos = lane & 15;                      // staging: dest position-group
    const int cneed = wave * 4 + (nl >> 2);          // consume: needed col-group

    const _Float16 ofv = high ? (_Float16)1055.0f : (_Float16)1039.0f;  // 1024+31 / 1024+15
    const half2 off = {ofv, ofv};

#pragma unroll 1
    for (int t = 0; t < 8; ++t) {
        const int Rt = R00 + t * RPT;
        // stage tile t: instr i covers rows 4i..4i+3; position-group p of
        // row r holds source col-group (p - r) & 15 (rotation -> 0-conflict reads)
        for (int i = wave; i < NI; i += 4) {
            const int r  = 4 * i + srow;
            const int cg = (spos - r) & 15;
            const int* gp = Wb + (size_t)(Rt + r) * NFEAT + n0 + cg * 4;
            GLOAD_LDS16(gp, &lds[i * 256]);
        }
        const float scf = Sb[(size_t)((kloc0 + t * 64) >> 7) * NFEAT + n];
        __syncthreads();                              // staging complete (vmcnt drain)

        const _Float16 s1 = (_Float16)scf;
        const half2 s2 = {s1, s1};
        const int sgb = ky * 16 + t * 2;              // global k>>5 of tile start
#pragma unroll
        for (int s = 0; s < 2; ++s) {
            const int r0 = high ? (24 * s + 6 * quad) : (20 * s + 5 * quad);
            const int NR = high ? 6 : 5;
            int b[6];
#pragma unroll
            for (int j = 0; j < 6; ++j) {
                if (j < NR) {
                    const int r = r0 + j;
                    const int p = (cneed + r) & 15;
                    b[j] = lds[r * 64 + p * 4 + (nl & 3)];
                }
            }
            int v0, v1, v2, v3, v4, v5, v6, v7;
            if (high) {
                v0 = b[0] & 63;
                v1 = ((b[0] >> 6) & 3) | ((b[1] & 15) << 2);
                v2 = ((b[1] >> 4) & 15) | ((b[2] & 3) << 4);
                v3 = (b[2] >> 2) & 63;
                v4 = b[3] & 63;
                v5 = ((b[3] >> 6) & 3) | ((b[4] & 15) << 2);
                v6 = ((b[4] >> 4) & 15) | ((b[5] & 3) << 4);
                v7 = (b[5] >> 2) & 63;
            } else {
                v0 = b[0] & 31;
                v1 = ((b[0] >> 5) & 7) | ((b[1] & 3) << 3);
                v2 = (b[1] >> 2) & 31;
                v3 = ((b[1] >> 7) & 1) | ((b[2] & 15) << 1);
                v4 = ((b[2] >> 4) & 15) | ((b[3] & 1) << 4);
                v5 = (b[3] >> 1) & 31;
                v6 = ((b[3] >> 6) & 3) | ((b[4] & 7) << 2);
                v7 = (b[4] >> 3) & 31;
            }
            H8 w;
            w.h[0] = dq2(v0, v1, off, s2);
            w.h[1] = dq2(v2, v3, off, s2);
            w.h[2] = dq2(v4, v5, off, s2);
            w.h[3] = dq2(v6, v7, off, s2);
            const int sg = sgb + s;
#pragma unroll
            for (int mt = 0; mt < 4; ++mt) {
                half8 a = *(const half8*)(xfrag + ((size_t)(sg * 4 + mt) * 64 + lane) * 8);
                acc[mt] = __builtin_amdgcn_mfma_f32_16x16x32_f16(a, w.v, acc[mt], 0, 0, 0);
            }
        }
        __syncthreads();                              // reads done before next stage
    }

    // ---- epilogue: D row = mt*16 + quad*4 + r, col = n ----
    const int rb = quad << 2;
    if (atomic_mode) {
#pragma unroll
        for (int mt = 0; mt < 4; ++mt)
#pragma unroll
            for (int r = 0; r < 4; ++r)
                atomicAdd(&dst[(size_t)(mt * 16 + rb + r) * NFEAT + n], acc[mt][r]);
    } else {
        float* o = dst + (size_t)ky * 64 * NFEAT;
#pragma unroll
        for (int mt = 0; mt < 4; ++mt)
#pragma unroll
            for (int r = 0; r < 4; ++r)
                o[(size_t)(mt * 16 + rb + r) * NFEAT + n] = acc[mt][r];
    }
}

// ---------------- reduce: out = bias + sum_p partial[p] ----------------
__global__ __launch_bounds__(256) void reduce_out(const float* __restrict__ part,
                                                  const float* __restrict__ bias,
                                                  float* __restrict__ out, int P) {
    const int idx = blockIdx.x * 256 + threadIdx.x;   // 0..176127 (f32x4 units)
    const int f   = idx * 4;
    const int nn  = f % NFEAT;                        // NFEAT%4==0 -> same row
    f32x4 s = *(const f32x4*)(bias + nn);
    for (int p = 0; p < P; ++p)
        s += *(const f32x4*)(part + (size_t)p * 704512 + f);
    *(f32x4*)(out + f) = s;
}

__global__ __launch_bounds__(256) void init_bias(const float* __restrict__ bias,
                                                 float* __restrict__ out) {
    const int idx = blockIdx.x * 256 + threadIdx.x;   // 0..704511
    out[idx] = bias[idx % NFEAT];
}

extern "C" void kernel_launch(void* const* d_in, const int* in_sizes, int n_in,
                              void* d_out, int out_size, void* d_ws, size_t ws_size,
                              hipStream_t stream) {
    const float* x    = (const float*)d_in[0];
    const int*   Wh   = (const int*)d_in[1];
    const int*   Wl   = (const int*)d_in[2];
    const float* sh   = (const float*)d_in[3];
    const float* sl   = (const float*)d_in[4];
    const int*   col  = (const int*)d_in[5];
    const float* bias = (const float*)d_in[6];
    float* out = (float*)d_out;

    _Float16* xfrag = (_Float16*)d_ws;                         // 512 KB
    const size_t xb      = (size_t)64 * KTOT * sizeof(_Float16);
    const size_t pstride = (size_t)64 * NFEAT;                 // floats per partial

    prep_xfrag<<<128, 256, 0, stream>>>(x, col, xfrag);

    if (ws_size >= xb + 8 * pstride * sizeof(float)) {
        float* part = (float*)((char*)d_ws + xb);
        gemm_kernel<<<dim3(172, 8), 256, 0, stream>>>(Wh, Wl, sh, sl, xfrag, part, 0);
        reduce_out<<<688, 256, 0, stream>>>(part, bias, out, 8);
    } else {
        init_bias<<<2752, 256, 0, stream>>>(bias, out);
        gemm_kernel<<<dim3(172, 8), 256, 0, stream>>>(Wh, Wl, sh, sl, xfrag, out, 1);
    }
}